// Round 11
// baseline (87.068 us; speedup 1.0000x reference)
//
#include <hip/hip_runtime.h>
#include <hip/hip_bf16.h>

#define B_    8
#define S_    4096
#define DIN   512
#define DOUT  64
#define NROWS (B_ * S_)   // 32768

typedef __attribute__((ext_vector_type(8)))  short bf16x8;
typedef __attribute__((ext_vector_type(4)))  float f32x4;
typedef __attribute__((ext_vector_type(16))) float f32x16;
typedef __attribute__((ext_vector_type(2)))  unsigned int u32x2;
typedef __attribute__((ext_vector_type(2)))  int i32x2;

typedef const __attribute__((address_space(1))) unsigned int GUI;
typedef __attribute__((address_space(3))) unsigned int LUI;

__device__ __forceinline__ unsigned short f32_to_bf16(float f) {
    union { float f; unsigned int u; } c; c.f = f;
    unsigned int r = (c.u + 0x7FFFu + ((c.u >> 16) & 1u)) >> 16;
    return (unsigned short)r;
}
__device__ __forceinline__ float bf16_to_f32(unsigned short us) {
    union { unsigned int u; float f; } c; c.u = (unsigned int)us << 16;
    return c.f;
}

__device__ __forceinline__ float fast_exp2(float x) {
#if __has_builtin(__builtin_amdgcn_exp2f)
    return __builtin_amdgcn_exp2f(x);
#else
    return exp2f(x);
#endif
}

// combined reductions with partner lane^32 (semantics pinned by round-7 A/B)
__device__ __forceinline__ float max_xor32(float v) {
    i32x2 r = __builtin_amdgcn_permlane32_swap(__float_as_int(v), __float_as_int(v),
                                               false, false);
    return fmaxf(__int_as_float(r.x), __int_as_float(r.y));
}
__device__ __forceinline__ float sum_xor32(float v) {
    i32x2 r = __builtin_amdgcn_permlane32_swap(__float_as_int(v), __float_as_int(v),
                                               false, false);
    return __int_as_float(r.x) + __int_as_float(r.y);
}

// Rule-18 fence (see r6): LDS reads of the buffer COMPLETE before the barrier
#define LDS_READS_DONE_FENCE() do {                                   \
    asm volatile("s_waitcnt lgkmcnt(0)" ::: "memory");                \
    __builtin_amdgcn_sched_barrier(0);                                \
} while (0)

// chunks per batch for a given KV-chunk size (in 64-row tiles)
constexpr int cpbf(int C) {
    int a = 0;
    for (int t = 0; t < 32; ++t) a += (2 * t + 2 + C - 1) / C;
    return a;
}

// ---------------------------------------------------------------------------
// Kernel 1: W -> Wt2 bf16 B-frag order (unchanged).
// ---------------------------------------------------------------------------
__global__ void wt_convert(const float* __restrict__ WQ,
                           const float* __restrict__ WK,
                           const float* __restrict__ WV,
                           unsigned short* __restrict__ Wt2) {
    int idx = blockIdx.x * 256 + threadIdx.x;
    if (idx >= 3 * 512 * 16) return;
    int p   = idx / 8192;
    int rem = idx - p * 8192;
    int k   = rem >> 4;
    int n0  = (rem & 15) * 4;
    const float* W = (p == 0) ? WQ : ((p == 1) ? WK : WV);
    float4 v = *(const float4*)(W + k * 64 + n0);
    const int ks = k >> 5, kl = k & 31;
    float vv[4] = {v.x, v.y, v.z, v.w};
#pragma unroll
    for (int r = 0; r < 4; ++r) {
        int n = n0 + r;
        Wt2[(size_t)((ks * 12 + p * 4 + (n >> 4)) * 512) + (n & 15) * 32 + kl] =
            f32_to_bf16(vv[r]);
    }
}

// ---------------------------------------------------------------------------
// Kernel 2: fused QKV projection (unchanged — proven correct).
// ---------------------------------------------------------------------------
__global__ __launch_bounds__(256) void qkv_proj(const float* __restrict__ x,
                                                const unsigned short* __restrict__ Wt2,
                                                unsigned short* __restrict__ QKV) {
    __shared__ alignas(16) float          xtile[2][1024];
    __shared__ alignas(16) unsigned short btile[2][6144];

    const int tid  = threadIdx.x;
    const int lane = tid & 63;
    const int wq   = tid >> 6;
    const int c15  = lane & 15;
    const int g    = lane >> 4;
    const float* xblk = x + (size_t)blockIdx.x * 32 * DIN;

    const int rw     = (wq & 1) * 16 + c15;
    const int nfbase = (wq >> 1) * 6;

    const int xrow = wq * 8 + (lane >> 3);
    const int xsl  = (lane & 7) ^ (xrow & 7);

    auto stage = [&](int slot, int ks) {
        __builtin_amdgcn_global_load_lds((GUI*)(xblk + ks * 32 + xrow * DIN + xsl * 4),
                                         (LUI*)((char*)&xtile[slot][0] + wq * 1024), 16, 0, 0);
        const unsigned short* Bs = Wt2 + (size_t)ks * 6144;
#pragma unroll
        for (int j = 0; j < 3; ++j)
            __builtin_amdgcn_global_load_lds((GUI*)(Bs + (j * 256 + tid) * 8),
                                             (LUI*)((char*)&btile[slot][0] + j * 4096 + wq * 1024),
                                             16, 0, 0);
    };
    stage(0, 0);
    stage(1, 1);

    f32x4 acc[6] = {};

    int cur = 0;
    for (int ks = 0; ks < 16; ++ks) {
        asm volatile("s_waitcnt vmcnt(4)" ::: "memory");
        asm volatile("s_barrier" ::: "memory");

        const char* xb = (const char*)&xtile[cur][0] + rw * 128;
        f32x4 a0 = *(const f32x4*)(xb + (((2 * g)     ^ (rw & 7)) << 4));
        f32x4 a1 = *(const f32x4*)(xb + (((2 * g + 1) ^ (rw & 7)) << 4));
        union { unsigned w[4]; bf16x8 v; } af;
        asm("v_cvt_pk_bf16_f32 %0, %1, %2" : "=v"(af.w[0]) : "v"(a0[0]), "v"(a0[1]));
        asm("v_cvt_pk_bf16_f32 %0, %1, %2" : "=v"(af.w[1]) : "v"(a0[2]), "v"(a0[3]));
        asm("v_cvt_pk_bf16_f32 %0, %1, %2" : "=v"(af.w[2]) : "v"(a1[0]), "v"(a1[1]));
        asm("v_cvt_pk_bf16_f32 %0, %1, %2" : "=v"(af.w[3]) : "v"(a1[2]), "v"(a1[3]));

        const char* bb = (const char*)&btile[cur][0] + c15 * 64 + g * 16;
#pragma unroll
        for (int n = 0; n < 6; ++n) {
            bf16x8 bf = *(const bf16x8*)(bb + (nfbase + n) * 1024);
            acc[n] = __builtin_amdgcn_mfma_f32_16x16x32_bf16(af.v, bf, acc[n], 0, 0, 0);
        }

        LDS_READS_DONE_FENCE();
        asm volatile("s_barrier" ::: "memory");
        {
            int tn = ks + 2; if (tn > 15) tn = 15;
            stage(cur, tn);
        }
        cur ^= 1;
    }
    asm volatile("s_waitcnt vmcnt(0)" ::: "memory");

    const int orow0 = blockIdx.x * 32 + (wq & 1) * 16 + g * 4;
#pragma unroll
    for (int n = 0; n < 6; ++n) {
        const int nfg  = nfbase + n;
        const int p    = nfg >> 2;
        const int ncol = (nfg & 3) * 16 + c15;
        if (p < 2) {
            unsigned short* outp = QKV + (size_t)p * NROWS * DOUT;
            const float sc = (p == 0) ? 0.125f * 1.44269504089f : 1.0f;
#pragma unroll
            for (int r = 0; r < 4; ++r)
                outp[(size_t)(orow0 + r) * DOUT + ncol] = f32_to_bf16(acc[n][r] * sc);
        } else {
            const int bb2  = orow0 >> 12;
            const int srow = orow0 & 4095;
            union { unsigned short s[4]; u32x2 d; } pk;
#pragma unroll
            for (int r = 0; r < 4; ++r) pk.s[r] = f32_to_bf16(acc[n][r]);
            *(u32x2*)(QKV + (size_t)2 * NROWS * DOUT +
                      ((size_t)bb2 * DOUT + ncol) * S_ + srow) = pk.d;
        }
    }
}

// ---------------------------------------------------------------------------
// Kernel 3: causal flash attention, 32x32 MFMA, S^T/O^T, in-register P.
// Template CHUNK = KV-tiles per block. Grid = 8 * cpbf(CHUNK).
// Block-uniform scalar loop maps chunk index -> (tp, j). Defer-rescale (T13).
// ---------------------------------------------------------------------------
template<int CHUNK>
__global__ __launch_bounds__(256) void attn_fwd(const unsigned short* __restrict__ QKV,
                                                float* __restrict__ out,
                                                char* __restrict__ part1,
                                                float* __restrict__ ml0) {
    constexpr int PPB = cpbf(CHUNK) - 32;   // j>=1 partials per batch

    __shared__ alignas(16) unsigned short k_lds[2][4096]; // K[kv][d], swz slots
    __shared__ alignas(16) unsigned short v_lds[2][4096]; // V^T[d][kv], swz slots

    const int bid = blockIdx.x;
    const int b   = bid & 7;
    const int c   = bid >> 3;             // chunk index within batch

    int tp = 0, acc = 0, nck = 1;
    for (; tp < 32; ++tp) {
        nck = (2 * tp + 2 + CHUNK - 1) / CHUNK;
        if (c < acc + nck) break;
        acc += nck;
    }
    const int j        = c - acc;
    const int tile_lo  = CHUNK * j;
    const int tile_hi  = min(CHUNK * j + CHUNK - 1, 2 * tp + 1);
    const int tile_cnt = tile_hi - tile_lo + 1;   // even, >= 2
    const int qb       = tp * 128;

    const int tid  = threadIdx.x;
    const int lane = tid & 63;
    const int wq   = tid >> 6;
    const int q31  = lane & 31;
    const int h    = lane >> 5;
    const int swz  = q31 & 7;
    const int rb0  = q31 * 128;

    const unsigned short* Qg  = QKV + (size_t)b * S_ * DOUT;
    const unsigned short* Kg  = QKV + (size_t)NROWS * DOUT + (size_t)b * S_ * DOUT;
    const unsigned short* VTg = QKV + (size_t)2 * NROWS * DOUT + (size_t)b * DOUT * S_;

    const int qrow = qb + wq * 32 + q31;
    const unsigned short* Qr = Qg + (size_t)qrow * DOUT + 8 * h;
    bf16x8 qf[4];
#pragma unroll
    for (int s = 0; s < 4; ++s) qf[s] = *(const bf16x8*)(Qr + 16 * s);
    asm volatile("s_waitcnt vmcnt(0)" ::: "memory");  // exact vmcnt bookkeeping

    const int i0 = wq * 128 + lane;
    const int i1 = i0 + 64;
    const int r0 = i0 >> 3, s0g = (i0 & 7) ^ (r0 & 7);
    const int r1 = i1 >> 3, s1g = (i1 & 7) ^ (r1 & 7);

    auto stage = [&](int slot, int tg) {
        const unsigned short* Kt = Kg + (size_t)tg * 64 * DOUT;
        const unsigned short* Vt = VTg + tg * 64;
        char* kbase = (char*)&k_lds[slot][0] + wq * 2048;
        char* vbase = (char*)&v_lds[slot][0] + wq * 2048;
        __builtin_amdgcn_global_load_lds((GUI*)(Kt + r0 * DOUT + s0g * 8), (LUI*)kbase, 16, 0, 0);
        __builtin_amdgcn_global_load_lds((GUI*)(Kt + r1 * DOUT + s1g * 8), (LUI*)(kbase + 1024), 16, 0, 0);
        __builtin_amdgcn_global_load_lds((GUI*)(Vt + (size_t)r0 * S_ + s0g * 8), (LUI*)vbase, 16, 0, 0);
        __builtin_amdgcn_global_load_lds((GUI*)(Vt + (size_t)r1 * S_ + s1g * 8), (LUI*)(vbase + 1024), 16, 0, 0);
    };

    stage(0, tile_lo);
    stage(1, tile_lo + 1);

    f32x16 oacc0 = {}, oacc1 = {};
    float m_r = -3.0e38f, l_r = 0.f;

    int cur = 0;
    for (int itl = 0; itl < tile_cnt; ++itl) {
        const int tg = tile_lo + itl;
        asm volatile("s_waitcnt vmcnt(4)" ::: "memory");
        asm volatile("s_barrier" ::: "memory");

        const char* kb_ = (const char*)&k_lds[cur][0];
        const char* vb_ = (const char*)&v_lds[cur][0];

        // --- S^T = mfma(K, Q): lane (q31,h): S^T[kv = 32kb + c+8e+4h][q31] ---
        f32x16 sA = {}, sB = {};
#pragma unroll
        for (int s = 0; s < 4; ++s) {
            const int sl = ((2 * s + h) ^ swz) << 4;
            bf16x8 ka  = *(const bf16x8*)(kb_ + rb0 + sl);
            bf16x8 kb2 = *(const bf16x8*)(kb_ + rb0 + 4096 + sl);
            sA = __builtin_amdgcn_mfma_f32_32x32x16_bf16(ka,  qf[s], sA, 0, 0, 0);
            sB = __builtin_amdgcn_mfma_f32_32x32x16_bf16(kb2, qf[s], sB, 0, 0, 0);
        }

        // --- causal mask (only tiles 2tp / 2tp+1) ---
        if (tg >= 2 * tp) {
#pragma unroll
            for (int r2 = 0; r2 < 16; ++r2) {
                const int kvg = 64 * tg + (r2 & 3) + 8 * (r2 >> 2) + 4 * h;
                if (kvg      > qrow) sA[r2] = -1.0e30f;
                if (kvg + 32 > qrow) sB[r2] = -1.0e30f;
            }
        }

        // --- lane-local online softmax with defer-rescale (T13) ---
        float t[16];
#pragma unroll
        for (int k2 = 0; k2 < 16; ++k2) t[k2] = fmaxf(sA[k2], sB[k2]);
#pragma unroll
        for (int st = 8; st >= 1; st >>= 1)
#pragma unroll
            for (int k2 = 0; k2 < st; ++k2) t[k2] = fmaxf(t[k2], t[k2 + st]);
        const float mx = max_xor32(t[0]);

        if (__any(mx > m_r + 11.5f)) {    // 11.5 = 8 nats in exp2 domain
            const float mnew  = fmaxf(m_r, mx);
            const float alpha = fast_exp2(m_r - mnew);
            m_r = mnew;
            l_r *= alpha;
#pragma unroll
            for (int k2 = 0; k2 < 16; ++k2) { oacc0[k2] *= alpha; oacc1[k2] *= alpha; }
        }

#pragma unroll
        for (int k2 = 0; k2 < 16; ++k2) {
            sA[k2] = fast_exp2(sA[k2] - m_r);
            sB[k2] = fast_exp2(sB[k2] - m_r);
        }
#pragma unroll
        for (int k2 = 0; k2 < 16; ++k2) t[k2] = sA[k2] + sB[k2];
#pragma unroll
        for (int st = 8; st >= 1; st >>= 1)
#pragma unroll
            for (int k2 = 0; k2 < st; ++k2) t[k2] += t[k2 + st];
        l_r += sum_xor32(t[0]);

        // --- P pack (T12) + PV, per 16-kv step u; no LDS for P ---
#define STEP_PV(u, Pv) do {                                                        \
        const int e0 = 2 * ((u) & 1);                                              \
        unsigned pa, pb2, pc, pd;                                                  \
        asm("v_cvt_pk_bf16_f32 %0, %1, %2" : "=v"(pa)  : "v"(Pv[4*e0+0]), "v"(Pv[4*e0+1])); \
        asm("v_cvt_pk_bf16_f32 %0, %1, %2" : "=v"(pb2) : "v"(Pv[4*e0+2]), "v"(Pv[4*e0+3])); \
        asm("v_cvt_pk_bf16_f32 %0, %1, %2" : "=v"(pc)  : "v"(Pv[4*e0+4]), "v"(Pv[4*e0+5])); \
        asm("v_cvt_pk_bf16_f32 %0, %1, %2" : "=v"(pd)  : "v"(Pv[4*e0+6]), "v"(Pv[4*e0+7])); \
        i32x2 ra = __builtin_amdgcn_permlane32_swap((int)pa,  (int)pc, false, false); \
        i32x2 rb = __builtin_amdgcn_permlane32_swap((int)pb2, (int)pd, false, false); \
        union { unsigned w[4]; bf16x8 v; } pw;                                     \
        pw.w[0] = (unsigned)ra.x; pw.w[1] = (unsigned)rb.x;                        \
        pw.w[2] = (unsigned)ra.y; pw.w[3] = (unsigned)rb.y;                        \
        const int slv = ((2 * (u) + h) ^ swz) << 4;                                \
        bf16x8 vfa = *(const bf16x8*)(vb_ + rb0 + slv);                            \
        bf16x8 vfb = *(const bf16x8*)(vb_ + rb0 + 4096 + slv);                     \
        oacc0 = __builtin_amdgcn_mfma_f32_32x32x16_bf16(vfa, pw.v, oacc0, 0, 0, 0);\
        oacc1 = __builtin_amdgcn_mfma_f32_32x32x16_bf16(vfb, pw.v, oacc1, 0, 0, 0);\
    } while (0)

        STEP_PV(0, sA); STEP_PV(1, sA); STEP_PV(2, sB); STEP_PV(3, sB);
#undef STEP_PV

        LDS_READS_DONE_FENCE();
        asm volatile("s_barrier" ::: "memory");
        {
            int tn = itl + 2; if (tn >= tile_cnt) tn = tile_cnt - 1;
            stage(cur, tile_lo + tn);
        }
        cur ^= 1;
    }

    asm volatile("s_waitcnt vmcnt(0)" ::: "memory");   // drain LDS-DMA pre-endpgm

    // O^T lane map: d = 32*db + (reg&3) + 8*(reg>>2) + 4*h, q = q31
    const int ql = wq * 32 + q31;
    if (nck == 1) {
        const float linv = 1.0f / l_r;
        float* op = out + (size_t)b * S_ * DOUT + (size_t)qrow * DOUT;
#pragma unroll
        for (int e = 0; e < 4; ++e) {
            f32x4 v0 = { oacc0[4*e+0]*linv, oacc0[4*e+1]*linv, oacc0[4*e+2]*linv, oacc0[4*e+3]*linv };
            f32x4 v1 = { oacc1[4*e+0]*linv, oacc1[4*e+1]*linv, oacc1[4*e+2]*linv, oacc1[4*e+3]*linv };
            *(f32x4*)(op + 8*e + 4*h)      = v0;
            *(f32x4*)(op + 32 + 8*e + 4*h) = v1;
        }
    } else if (j == 0) {
        float* op = out + (size_t)b * S_ * DOUT + (size_t)qrow * DOUT;
#pragma unroll
        for (int e = 0; e < 4; ++e) {
            f32x4 v0 = { oacc0[4*e+0], oacc0[4*e+1], oacc0[4*e+2], oacc0[4*e+3] };
            f32x4 v1 = { oacc1[4*e+0], oacc1[4*e+1], oacc1[4*e+2], oacc1[4*e+3] };
            *(f32x4*)(op + 8*e + 4*h)      = v0;
            *(f32x4*)(op + 32 + 8*e + 4*h) = v1;
        }
        if (h == 0) {
            float* ml = ml0 + (size_t)(b * 32 + tp) * 256;
            ml[ql] = m_r; ml[128 + ql] = l_r;
        }
    } else {
        char* pb_ = part1 + (size_t)(b * PPB + (acc - tp) + (j - 1)) * 17408;
        if (h == 0) {
            float* mf = (float*)pb_;
            mf[ql] = m_r; mf[128 + ql] = l_r;
        }
        unsigned short* ob = (unsigned short*)(pb_ + 1024);
#pragma unroll
        for (int e = 0; e < 4; ++e) {
            union { unsigned short s[4]; u32x2 d; } k0, k1;
#pragma unroll
            for (int cc = 0; cc < 4; ++cc) { k0.s[cc] = f32_to_bf16(oacc0[4*e+cc]);
                                             k1.s[cc] = f32_to_bf16(oacc1[4*e+cc]); }
            *(u32x2*)(ob + (size_t)ql * 64 + 8*e + 4*h)      = k0.d;
            *(u32x2*)(ob + (size_t)ql * 64 + 32 + 8*e + 4*h) = k1.d;
        }
    }
}

// ---------------------------------------------------------------------------
// Kernel 4: combine KV-chunks. Rule-20-safe: two passes over partials reading
// memory directly (no runtime-indexed register arrays). Grid 8192 =
// 8 b x 32 tp x 32 q-subtiles; 256 thr = 4 q x 64 d; nck==1 tiles early-out.
// ---------------------------------------------------------------------------
template<int CHUNK>
__global__ __launch_bounds__(256) void attn_reduce(float* __restrict__ out,
                                                   const char* __restrict__ part1,
                                                   const float* __restrict__ ml0) {
    constexpr int PPB = cpbf(CHUNK) - 32;

    const int bid = blockIdx.x;
    const int sub = bid & 31;
    const int tp  = (bid >> 5) & 31;
    const int b   = bid >> 10;

    const int nck = (2 * tp + 2 + CHUNK - 1) / CHUNK;
    if (nck < 2) return;
    int acc = 0;
    for (int t2 = 0; t2 < tp; ++t2) acc += (2 * t2 + 2 + CHUNK - 1) / CHUNK;
    const int pbase = acc - tp;

    const int q = sub * 4 + (threadIdx.x >> 6);
    const int d = threadIdx.x & 63;

    float* otile = out + ((size_t)b * S_ + (size_t)tp * 128) * 64;
    const float* ml = ml0 + (size_t)(b * 32 + tp) * 256;

    float M = ml[q];
    for (int jj = 1; jj < nck; ++jj) {
        const float* mf = (const float*)(part1 + (size_t)(b * PPB + pbase + jj - 1) * 17408);
        M = fmaxf(M, mf[q]);
    }
    const float e0 = fast_exp2(ml[q] - M);
    float L = e0 * ml[128 + q];
    float O = e0 * otile[(size_t)q * 64 + d];
    for (int jj = 1; jj < nck; ++jj) {
        const char* pb = part1 + (size_t)(b * PPB + pbase + jj - 1) * 17408;
        const float* mf = (const float*)pb;
        const float ej = fast_exp2(mf[q] - M);
        L += ej * mf[128 + q];
        O += ej * bf16_to_f32(((const unsigned short*)(pb + 1024))[(size_t)q * 64 + d]);
    }
    otile[(size_t)q * 64 + d] = O / L;
}

// ---------------------------------------------------------------------------
extern "C" void kernel_launch(void* const* d_in, const int* in_sizes, int n_in,
                              void* d_out, int out_size, void* d_ws, size_t ws_size,
                              hipStream_t stream) {
    const float* x  = (const float*)d_in[0];
    const float* WQ = (const float*)d_in[1];
    const float* WK = (const float*)d_in[2];
    const float* WV = (const float*)d_in[3];

    unsigned short* Wt2   = (unsigned short*)d_ws;             // 192 KB
    unsigned short* QKV   = Wt2 + 192 * 512;                   // 12 MB: Q | K | V^T
    char*           part1 = (char*)d_ws + 12779520;
    float* out = (float*)d_out;

    wt_convert<<<96, 256, 0, stream>>>(WQ, WK, WV, Wt2);
    qkv_proj<<<1024, 256, 0, stream>>>(x, Wt2, QKV);

    constexpr size_t P8  = (size_t)8 * (cpbf(8)  - 32) * 17408;  // 15.60 MB
    constexpr size_t P16 = (size_t)8 * (cpbf(16) - 32) * 17408;  //  6.68 MB
    constexpr size_t ML  = (size_t)8 * 32 * 1024;                // 256 KB
    const size_t need8 = 12779520 + P8 + ML;                     // 28.64 MB

    if (ws_size >= need8) {
        float* ml0 = (float*)(part1 + P8);
        attn_fwd<8><<<8 * cpbf(8), 256, 0, stream>>>(QKV, out, part1, ml0);
        attn_reduce<8><<<8192, 256, 0, stream>>>(out, part1, ml0);
    } else {
        float* ml0 = (float*)(part1 + P16);
        attn_fwd<16><<<8 * cpbf(16), 256, 0, stream>>>(QKV, out, part1, ml0);
        attn_reduce<16><<<8192, 256, 0, stream>>>(out, part1, ml0);
    }
}

// Round 12
// 71.193 us; speedup vs baseline: 1.2230x; 1.2230x over previous
//
#include <hip/hip_runtime.h>
#include <hip/hip_bf16.h>

#define B_    8
#define S_    4096
#define DIN   512
#define DOUT  64
#define NROWS (B_ * S_)   // 32768

typedef __attribute__((ext_vector_type(8)))  short bf16x8;
typedef __attribute__((ext_vector_type(4)))  float f32x4;
typedef __attribute__((ext_vector_type(2)))  unsigned int u32x2;
typedef __attribute__((ext_vector_type(2)))  int i32x2;

typedef const __attribute__((address_space(1))) unsigned int GUI;
typedef __attribute__((address_space(3))) unsigned int LUI;

__device__ __forceinline__ unsigned short f32_to_bf16(float f) {
    union { float f; unsigned int u; } c; c.f = f;
    unsigned int r = (c.u + 0x7FFFu + ((c.u >> 16) & 1u)) >> 16;
    return (unsigned short)r;
}
__device__ __forceinline__ float bf16_to_f32(unsigned short us) {
    union { unsigned int u; float f; } c; c.u = (unsigned int)us << 16;
    return c.f;
}

__device__ __forceinline__ float fast_exp2(float x) {
#if __has_builtin(__builtin_amdgcn_exp2f)
    return __builtin_amdgcn_exp2f(x);
#else
    return exp2f(x);
#endif
}

// combined reductions with partner lane^32 (semantics pinned by round-7 A/B)
__device__ __forceinline__ float max_xor32(float v) {
    i32x2 r = __builtin_amdgcn_permlane32_swap(__float_as_int(v), __float_as_int(v),
                                               false, false);
    return fmaxf(__int_as_float(r.x), __int_as_float(r.y));
}
__device__ __forceinline__ float sum_xor32(float v) {
    i32x2 r = __builtin_amdgcn_permlane32_swap(__float_as_int(v), __float_as_int(v),
                                               false, false);
    return __int_as_float(r.x) + __int_as_float(r.y);
}

// Rule-18 fence (see r6): LDS reads of the buffer COMPLETE before the barrier
#define LDS_READS_DONE_FENCE() do {                                   \
    asm volatile("s_waitcnt lgkmcnt(0)" ::: "memory");                \
    __builtin_amdgcn_sched_barrier(0);                                \
} while (0)

// partial-chunk index for j>=1 (tp>=8); 48 entries per batch (r10 proven)
__device__ __forceinline__ int pidx_of(int tp, int j) {
    if (tp < 16) return tp - 8;                      // j==1
    if (tp < 24) return 8 + (tp - 16) * 2 + (j - 1); // j in {1,2}
    return 24 + (tp - 24) * 3 + (j - 1);             // j in {1,2,3}
}

// ---------------------------------------------------------------------------
// Kernel 1: W -> Wt2 bf16 B-frag order (unchanged).
// ---------------------------------------------------------------------------
__global__ void wt_convert(const float* __restrict__ WQ,
                           const float* __restrict__ WK,
                           const float* __restrict__ WV,
                           unsigned short* __restrict__ Wt2) {
    int idx = blockIdx.x * 256 + threadIdx.x;
    if (idx >= 3 * 512 * 16) return;
    int p   = idx / 8192;
    int rem = idx - p * 8192;
    int k   = rem >> 4;
    int n0  = (rem & 15) * 4;
    const float* W = (p == 0) ? WQ : ((p == 1) ? WK : WV);
    float4 v = *(const float4*)(W + k * 64 + n0);
    const int ks = k >> 5, kl = k & 31;
    float vv[4] = {v.x, v.y, v.z, v.w};
#pragma unroll
    for (int r = 0; r < 4; ++r) {
        int n = n0 + r;
        Wt2[(size_t)((ks * 12 + p * 4 + (n >> 4)) * 512) + (n & 15) * 32 + kl] =
            f32_to_bf16(vv[r]);
    }
}

// ---------------------------------------------------------------------------
// Kernel 2: fused QKV projection (unchanged — proven correct).
// ---------------------------------------------------------------------------
__global__ __launch_bounds__(256) void qkv_proj(const float* __restrict__ x,
                                                const unsigned short* __restrict__ Wt2,
                                                unsigned short* __restrict__ QKV) {
    __shared__ alignas(16) float          xtile[2][1024];
    __shared__ alignas(16) unsigned short btile[2][6144];

    const int tid  = threadIdx.x;
    const int lane = tid & 63;
    const int wq   = tid >> 6;
    const int c15  = lane & 15;
    const int g    = lane >> 4;
    const float* xblk = x + (size_t)blockIdx.x * 32 * DIN;

    const int rw     = (wq & 1) * 16 + c15;
    const int nfbase = (wq >> 1) * 6;

    const int xrow = wq * 8 + (lane >> 3);
    const int xsl  = (lane & 7) ^ (xrow & 7);

    auto stage = [&](int slot, int ks) {
        __builtin_amdgcn_global_load_lds((GUI*)(xblk + ks * 32 + xrow * DIN + xsl * 4),
                                         (LUI*)((char*)&xtile[slot][0] + wq * 1024), 16, 0, 0);
        const unsigned short* Bs = Wt2 + (size_t)ks * 6144;
#pragma unroll
        for (int j = 0; j < 3; ++j)
            __builtin_amdgcn_global_load_lds((GUI*)(Bs + (j * 256 + tid) * 8),
                                             (LUI*)((char*)&btile[slot][0] + j * 4096 + wq * 1024),
                                             16, 0, 0);
    };
    stage(0, 0);
    stage(1, 1);

    f32x4 acc[6] = {};

    int cur = 0;
    for (int ks = 0; ks < 16; ++ks) {
        asm volatile("s_waitcnt vmcnt(4)" ::: "memory");
        asm volatile("s_barrier" ::: "memory");

        const char* xb = (const char*)&xtile[cur][0] + rw * 128;
        f32x4 a0 = *(const f32x4*)(xb + (((2 * g)     ^ (rw & 7)) << 4));
        f32x4 a1 = *(const f32x4*)(xb + (((2 * g + 1) ^ (rw & 7)) << 4));
        union { unsigned w[4]; bf16x8 v; } af;
        asm("v_cvt_pk_bf16_f32 %0, %1, %2" : "=v"(af.w[0]) : "v"(a0[0]), "v"(a0[1]));
        asm("v_cvt_pk_bf16_f32 %0, %1, %2" : "=v"(af.w[1]) : "v"(a0[2]), "v"(a0[3]));
        asm("v_cvt_pk_bf16_f32 %0, %1, %2" : "=v"(af.w[2]) : "v"(a1[0]), "v"(a1[1]));
        asm("v_cvt_pk_bf16_f32 %0, %1, %2" : "=v"(af.w[3]) : "v"(a1[2]), "v"(a1[3]));

        const char* bb = (const char*)&btile[cur][0] + c15 * 64 + g * 16;
#pragma unroll
        for (int n = 0; n < 6; ++n) {
            bf16x8 bf = *(const bf16x8*)(bb + (nfbase + n) * 1024);
            acc[n] = __builtin_amdgcn_mfma_f32_16x16x32_bf16(af.v, bf, acc[n], 0, 0, 0);
        }

        LDS_READS_DONE_FENCE();
        asm volatile("s_barrier" ::: "memory");
        {
            int tn = ks + 2; if (tn > 15) tn = 15;
            stage(cur, tn);
        }
        cur ^= 1;
    }
    asm volatile("s_waitcnt vmcnt(0)" ::: "memory");

    const int orow0 = blockIdx.x * 32 + (wq & 1) * 16 + g * 4;
#pragma unroll
    for (int n = 0; n < 6; ++n) {
        const int nfg  = nfbase + n;
        const int p    = nfg >> 2;
        const int ncol = (nfg & 3) * 16 + c15;
        if (p < 2) {
            unsigned short* outp = QKV + (size_t)p * NROWS * DOUT;
            const float sc = (p == 0) ? 0.125f * 1.44269504089f : 1.0f;
#pragma unroll
            for (int r = 0; r < 4; ++r)
                outp[(size_t)(orow0 + r) * DOUT + ncol] = f32_to_bf16(acc[n][r] * sc);
        } else {
            const int bb2  = orow0 >> 12;
            const int srow = orow0 & 4095;
            union { unsigned short s[4]; u32x2 d; } pk;
#pragma unroll
            for (int r = 0; r < 4; ++r) pk.s[r] = f32_to_bf16(acc[n][r]);
            *(u32x2*)(QKV + (size_t)2 * NROWS * DOUT +
                      ((size_t)bb2 * DOUT + ncol) * S_ + srow) = pk.d;
        }
    }
}

// ---------------------------------------------------------------------------
// Kernel 3: causal flash attention. 8 waves x 16 q-rows (512 thr, 128 q/blk),
// 16x16x32 MFMAs (r8-proven fragments, VGPR ~56 -> no register occupancy cap),
// LDS 48KB -> 3 blocks/CU = 24 waves/CU. Chunked split-KV (16 tiles), r10
// bookkeeping. T13 defer-rescale + T5 setprio around MFMA clusters.
// ---------------------------------------------------------------------------
__global__ __launch_bounds__(512) void attn_fwd(const unsigned short* __restrict__ QKV,
                                                float* __restrict__ out,
                                                char* __restrict__ part1,
                                                float* __restrict__ ml0) {
    __shared__ alignas(16) unsigned short k_lds[2][4096]; // K[kv][8 slots], slot^=(kv&7)
    __shared__ alignas(16) unsigned short v_lds[2][4096]; // V^T[d][8 slots], slot^=(d&7)
    __shared__ alignas(16) unsigned short p_lds[8][1024]; // per-wave P, swizzled

    const int bid = blockIdx.x;
    const int b   = bid & 7;
    const int i   = bid >> 3;             // 0..79
    int tp, j;
    if      (i < 8)  { tp = i;                   j = 0; }
    else if (i < 24) { tp = 8 + ((i - 8) >> 1);  j = (i - 8) & 1; }
    else if (i < 48) { tp = 16 + (i - 24) / 3;   j = (i - 24) % 3; }
    else             { tp = 24 + ((i - 48) >> 2); j = (i - 48) & 3; }
    const int qb       = tp * 128;
    const int tile_lo  = 16 * j;
    const int tile_hi  = min(16 * j + 15, 2 * tp + 1);
    const int tile_cnt = tile_hi - tile_lo + 1;   // >= 2

    const int tid  = threadIdx.x;
    const int lane = tid & 63;
    const int wq   = tid >> 6;            // 0..7
    const int c15  = lane & 15;
    const int g    = lane >> 4;

    const unsigned short* Qg  = QKV + (size_t)b * S_ * DOUT;
    const unsigned short* Kg  = QKV + (size_t)NROWS * DOUT + (size_t)b * S_ * DOUT;
    const unsigned short* VTg = QKV + (size_t)2 * NROWS * DOUT + (size_t)b * DOUT * S_;

    const int ql   = wq * 16 + c15;       // 0..127
    const int qrow = qb + ql;
    const size_t qoff = (size_t)qrow * DOUT;
    bf16x8 qf0 = *(const bf16x8*)(Qg + qoff + g * 8);
    bf16x8 qf1 = *(const bf16x8*)(Qg + qoff + 32 + g * 8);
    asm volatile("s_waitcnt vmcnt(0)" ::: "memory");  // exact vmcnt bookkeeping

    // staging: 512 threads x (1 K + 1 V) 16B chunks per tile
    const int row = tid >> 3;             // 0..63
    const int sl  = (tid & 7) ^ (row & 7);

    auto stage = [&](int slot, int tg) {
        const unsigned short* Kt = Kg + (size_t)tg * 64 * DOUT;
        const unsigned short* Vt = VTg + tg * 64;
        char* kbase = (char*)&k_lds[slot][0] + wq * 1024;
        char* vbase = (char*)&v_lds[slot][0] + wq * 1024;
        __builtin_amdgcn_global_load_lds((GUI*)(Kt + row * DOUT + sl * 8), (LUI*)kbase, 16, 0, 0);
        __builtin_amdgcn_global_load_lds((GUI*)(Vt + (size_t)row * S_ + sl * 8), (LUI*)vbase, 16, 0, 0);
    };

    stage(0, tile_lo);
    stage(1, tile_lo + 1);

    f32x4 oacc[4] = {};
    float m_r = -3.0e38f, l_r = 0.f;

    int cur = 0;
    for (int itl = 0; itl < tile_cnt; ++itl) {
        const int tg = tile_lo + itl;
        asm volatile("s_waitcnt vmcnt(2)" ::: "memory");
        asm volatile("s_barrier" ::: "memory");

        const char* kb = (const char*)&k_lds[cur][0];
        const char* vb = (const char*)&v_lds[cur][0];

        // --- S^T = mfma(K, Q): lane holds S^T[kv = 16nf+4g+r][q = c15] ---
        f32x4 s[4];
        __builtin_amdgcn_s_setprio(1);
#pragma unroll
        for (int nf = 0; nf < 4; ++nf) {
            const char* krow = kb + (nf * 16 + c15) * 128;
            bf16x8 kf0 = *(const bf16x8*)(krow + ((g ^ (c15 & 7)) << 4));
            bf16x8 kf1 = *(const bf16x8*)(krow + (((4 + g) ^ (c15 & 7)) << 4));
            f32x4 z = {};
            z = __builtin_amdgcn_mfma_f32_16x16x32_bf16(kf0, qf0, z, 0, 0, 0);
            z = __builtin_amdgcn_mfma_f32_16x16x32_bf16(kf1, qf1, z, 0, 0, 0);
            s[nf] = z;
        }
        __builtin_amdgcn_s_setprio(0);

        // --- causal mask (diagonal spans tiles 2tp and 2tp+1) ---
        if (tg >= 2 * tp) {
#pragma unroll
            for (int nf = 0; nf < 4; ++nf)
#pragma unroll
                for (int r = 0; r < 4; ++r)
                    if (64 * tg + 16 * nf + 4 * g + r > qrow) s[nf][r] = -1.0e30f;
        }

        // --- lane-local online softmax with defer-rescale (T13) ---
        float mx = s[0][0];
#pragma unroll
        for (int nf = 0; nf < 4; ++nf)
#pragma unroll
            for (int r = 0; r < 4; ++r) mx = fmaxf(mx, s[nf][r]);
        mx = max_xor32(mx);
        mx = fmaxf(mx, __shfl_xor(mx, 16, 64));

        if (__any(mx > m_r + 11.5f)) {    // 11.5 = 8 nats in exp2 domain
            const float mnew  = fmaxf(m_r, mx);
            const float alpha = fast_exp2(m_r - mnew);
            m_r = mnew;
            l_r *= alpha;
#pragma unroll
            for (int df = 0; df < 4; ++df)
#pragma unroll
                for (int r = 0; r < 4; ++r) oacc[df][r] *= alpha;
        }

        float p[4][4];
        float sum = 0.f;
#pragma unroll
        for (int nf = 0; nf < 4; ++nf)
#pragma unroll
            for (int r = 0; r < 4; ++r) {
                p[nf][r] = fast_exp2(s[nf][r] - m_r);
                sum += p[nf][r];
            }
        sum = sum_xor32(sum);
        sum += __shfl_xor(sum, 16, 64);
        l_r += sum;

        // --- P^T -> bf16 pairs into per-wave swizzled LDS (w = kv/2) ---
#pragma unroll
        for (int nf = 0; nf < 4; ++nf)
#pragma unroll
            for (int pr = 0; pr < 2; ++pr) {
                unsigned pw;
                asm("v_cvt_pk_bf16_f32 %0, %1, %2"
                    : "=v"(pw) : "v"(p[nf][2 * pr]), "v"(p[nf][2 * pr + 1]));
                const int w = 8 * nf + 2 * g + pr;
                *(unsigned*)((char*)&p_lds[wq][0] + c15 * 128 +
                             (((w >> 2) ^ (c15 & 7)) << 4) + (w & 3) * 4) = pw;
            }

        bf16x8 pf[2];
#pragma unroll
        for (int kk = 0; kk < 2; ++kk)
            pf[kk] = *(const bf16x8*)((char*)&p_lds[wq][0] + c15 * 128 +
                                      (((4 * kk + g) ^ (c15 & 7)) << 4));

        // --- O^T += mfma(V^T, P^T): lane holds O^T[d = 16df+4g+r][q = c15] ---
        __builtin_amdgcn_s_setprio(1);
#pragma unroll
        for (int df = 0; df < 4; ++df) {
            const char* vrow = vb + (df * 16 + c15) * 128;
            bf16x8 vf0 = *(const bf16x8*)(vrow + ((g ^ (c15 & 7)) << 4));
            bf16x8 vf1 = *(const bf16x8*)(vrow + (((4 + g) ^ (c15 & 7)) << 4));
            oacc[df] = __builtin_amdgcn_mfma_f32_16x16x32_bf16(vf0, pf[0], oacc[df], 0, 0, 0);
            oacc[df] = __builtin_amdgcn_mfma_f32_16x16x32_bf16(vf1, pf[1], oacc[df], 0, 0, 0);
        }
        __builtin_amdgcn_s_setprio(0);

        LDS_READS_DONE_FENCE();
        asm volatile("s_barrier" ::: "memory");
        {
            int tn = itl + 2; if (tn >= tile_cnt) tn = tile_cnt - 1;
            stage(cur, tile_lo + tn);
        }
        cur ^= 1;
    }

    asm volatile("s_waitcnt vmcnt(0)" ::: "memory");   // drain LDS-DMA pre-endpgm

    if (j == 0 && tp < 8) {
        // single-chunk tile: direct normalized write (d = 16df+4g+r contiguous x4)
        const float linv = 1.0f / l_r;
        float* op = out + (size_t)b * S_ * DOUT + (size_t)qrow * DOUT;
#pragma unroll
        for (int df = 0; df < 4; ++df) {
            f32x4 v = { oacc[df][0] * linv, oacc[df][1] * linv,
                        oacc[df][2] * linv, oacc[df][3] * linv };
            *(f32x4*)(op + df * 16 + 4 * g) = v;
        }
    } else if (j == 0) {
        // unnormalized f32 O in-place + m/l to ml0
        float* op = out + (size_t)b * S_ * DOUT + (size_t)qrow * DOUT;
#pragma unroll
        for (int df = 0; df < 4; ++df) {
            f32x4 v = { oacc[df][0], oacc[df][1], oacc[df][2], oacc[df][3] };
            *(f32x4*)(op + df * 16 + 4 * g) = v;
        }
        if (g == 0) {
            float* ml = ml0 + (size_t)(b * 24 + (tp - 8)) * 256;
            ml[ql] = m_r; ml[128 + ql] = l_r;
        }
    } else {
        // bf16 partial: [m f32[128] | l f32[128] | O bf16 [q][d] 128x64]
        char* pb_ = part1 + (size_t)(b * 48 + pidx_of(tp, j)) * 17408;
        if (g == 0) {
            float* mf = (float*)pb_;
            mf[ql] = m_r; mf[128 + ql] = l_r;
        }
        unsigned short* ob = (unsigned short*)(pb_ + 1024);
#pragma unroll
        for (int df = 0; df < 4; ++df) {
            union { unsigned short s2[4]; u32x2 d; } pk;
#pragma unroll
            for (int r = 0; r < 4; ++r) pk.s2[r] = f32_to_bf16(oacc[df][r]);
            *(u32x2*)(ob + (size_t)ql * 64 + df * 16 + 4 * g) = pk.d;
        }
    }
}

// ---------------------------------------------------------------------------
// Kernel 4: combine KV-chunks (r10 proven: templated NC, every index
// compile-time). Grid 6144 = 8 b x 24 tp x 32 q-subtiles; 256 thr = 4q x 64d.
// ---------------------------------------------------------------------------
template<int NC>
__device__ __forceinline__ void reduce_body(int b, int tp, int q, int d,
                                            float* __restrict__ out,
                                            const char* __restrict__ part1,
                                            const float* __restrict__ ml0) {
    float* otile = out + ((size_t)b * S_ + (size_t)tp * 128) * 64;
    const float* ml = ml0 + (size_t)(b * 24 + (tp - 8)) * 256;

    float m = ml[q], l = ml[128 + q];
    float M = m;
    float mj[NC - 1], lj[NC - 1];
    const unsigned short* obs[NC - 1];
#pragma unroll
    for (int jj = 0; jj < NC - 1; ++jj) {
        const char* pb = part1 + (size_t)(b * 48 + pidx_of(tp, jj + 1)) * 17408;
        const float* mf = (const float*)pb;
        mj[jj] = mf[q]; lj[jj] = mf[128 + q];
        obs[jj] = (const unsigned short*)(pb + 1024);
        M = fmaxf(M, mj[jj]);
    }
    const float e0 = fast_exp2(m - M);
    float L = e0 * l;
    float O = e0 * otile[(size_t)q * 64 + d];
#pragma unroll
    for (int jj = 0; jj < NC - 1; ++jj) {
        const float ej = fast_exp2(mj[jj] - M);
        L += ej * lj[jj];
        O += ej * bf16_to_f32(obs[jj][(size_t)q * 64 + d]);
    }
    otile[(size_t)q * 64 + d] = O / L;
}

__global__ __launch_bounds__(256) void attn_reduce(float* __restrict__ out,
                                                   const char* __restrict__ part1,
                                                   const float* __restrict__ ml0) {
    const int bid = blockIdx.x;          // 0..6143
    const int sub = bid & 31;
    const int tz  = (bid >> 5) % 24;
    const int b   = bid / (32 * 24);
    const int tp  = tz + 8;
    const int q   = sub * 4 + (threadIdx.x >> 6);
    const int d   = threadIdx.x & 63;

    if (tp < 16)      reduce_body<2>(b, tp, q, d, out, part1, ml0);
    else if (tp < 24) reduce_body<3>(b, tp, q, d, out, part1, ml0);
    else              reduce_body<4>(b, tp, q, d, out, part1, ml0);
}

// ---------------------------------------------------------------------------
extern "C" void kernel_launch(void* const* d_in, const int* in_sizes, int n_in,
                              void* d_out, int out_size, void* d_ws, size_t ws_size,
                              hipStream_t stream) {
    const float* x  = (const float*)d_in[0];
    const float* WQ = (const float*)d_in[1];
    const float* WK = (const float*)d_in[2];
    const float* WV = (const float*)d_in[3];

    unsigned short* Wt2   = (unsigned short*)d_ws;             // 192 KB
    unsigned short* QKV   = Wt2 + 192 * 512;                   // 12 MB: Q | K | V^T
    char*           part1 = (char*)d_ws + 12779520;            // 384 x 17408 B
    float*          ml0   = (float*)((char*)d_ws + 19464192);  // 192 KB

    wt_convert<<<96, 256, 0, stream>>>(WQ, WK, WV, Wt2);
    qkv_proj<<<1024, 256, 0, stream>>>(x, Wt2, QKV);
    attn_fwd<<<640, 512, 0, stream>>>(QKV, (float*)d_out, part1, ml0);
    attn_reduce<<<6144, 256, 0, stream>>>((float*)d_out, part1, ml0);
}